// Round 3
// baseline (1978.074 us; speedup 1.0000x reference)
//
#include <hip/hip_runtime.h>
#include <hip/hip_bf16.h>

#define DI 768
#define SS 2048
#define QK_ELEMS ((size_t)16384 * 768)

typedef float f32x4 __attribute__((ext_vector_type(4)));
typedef short s16x8 __attribute__((ext_vector_type(8)));
typedef short s16x4 __attribute__((ext_vector_type(4)));

static __device__ __forceinline__ unsigned short f2bf(float f) {
    union { float f; unsigned int u; } a; a.f = f;
    unsigned int r = (a.u + 0x7FFFu + ((a.u >> 16) & 1u)) >> 16; // RNE
    return (unsigned short)r;
}

// ---------------- projection: Q = x@wq (pre-scaled), K = x@wk, Vt = (x@wv)^T ----
__global__ __launch_bounds__(256) void proj_kernel(
    const float* __restrict__ x, const float* __restrict__ wq,
    const float* __restrict__ wk, const float* __restrict__ wv,
    unsigned short* __restrict__ ws)
{
    constexpr int LDT = 40;
    __shared__ unsigned short As[128 * LDT];
    __shared__ unsigned short Bs[128 * LDT];

    const int which = blockIdx.z;
    const float* w = (which == 0) ? wq : (which == 1) ? wk : wv;
    const int n0 = blockIdx.x * 128;
    const int m0 = blockIdx.y * 128;
    const int tid = threadIdx.x;
    const int lane = tid & 63, wid = tid >> 6;
    const int wr = wid >> 1, wc = wid & 1;
    const int r = lane & 15, g = lane >> 4;

    f32x4 acc[4][4];
    #pragma unroll
    for (int i = 0; i < 4; ++i)
        #pragma unroll
        for (int j = 0; j < 4; ++j) acc[i][j] = (f32x4){0.f, 0.f, 0.f, 0.f};

    for (int k0 = 0; k0 < DI; k0 += 32) {
        #pragma unroll
        for (int i = 0; i < 4; ++i) {
            int idx = tid + i * 256;
            int row = idx >> 3, c4 = (idx & 7) * 4;
            const float4 v = *(const float4*)(x + (size_t)(m0 + row) * DI + k0 + c4);
            ushort4 pk; pk.x = f2bf(v.x); pk.y = f2bf(v.y); pk.z = f2bf(v.z); pk.w = f2bf(v.w);
            *(ushort4*)&As[row * LDT + c4] = pk;
        }
        #pragma unroll
        for (int i = 0; i < 4; ++i) {
            int idx = tid + i * 256;
            int nn = (idx & 31) * 4, kk = idx >> 5;
            const float4 v = *(const float4*)(w + (size_t)(k0 + kk) * DI + n0 + nn);
            Bs[(nn + 0) * LDT + kk] = f2bf(v.x);
            Bs[(nn + 1) * LDT + kk] = f2bf(v.y);
            Bs[(nn + 2) * LDT + kk] = f2bf(v.z);
            Bs[(nn + 3) * LDT + kk] = f2bf(v.w);
        }
        __syncthreads();
        s16x8 af[4], bfr[4];
        #pragma unroll
        for (int fr = 0; fr < 4; ++fr)
            af[fr] = *(const s16x8*)&As[(wr * 64 + fr * 16 + r) * LDT + g * 8];
        #pragma unroll
        for (int cf = 0; cf < 4; ++cf)
            bfr[cf] = *(const s16x8*)&Bs[(wc * 64 + cf * 16 + r) * LDT + g * 8];
        #pragma unroll
        for (int fr = 0; fr < 4; ++fr)
            #pragma unroll
            for (int cf = 0; cf < 4; ++cf)
                acc[fr][cf] = __builtin_amdgcn_mfma_f32_16x16x32_bf16(af[fr], bfr[cf], acc[fr][cf], 0, 0, 0);
        __syncthreads();
    }

    const float scale = (which == 0) ? 0.03608439182435161f : 1.0f;
    if (which < 2) {
        unsigned short* O = ws + (size_t)which * QK_ELEMS;
        #pragma unroll
        for (int fr = 0; fr < 4; ++fr)
            #pragma unroll
            for (int cf = 0; cf < 4; ++cf) {
                int row = m0 + wr * 64 + fr * 16 + g * 4;
                int col = n0 + wc * 64 + cf * 16 + r;
                #pragma unroll
                for (int jj = 0; jj < 4; ++jj)
                    O[(size_t)(row + jj) * DI + col] = f2bf(acc[fr][cf][jj] * scale);
            }
    } else {
        unsigned short* O = ws + 2 * QK_ELEMS; // Vt[b][e][s]
        #pragma unroll
        for (int fr = 0; fr < 4; ++fr)
            #pragma unroll
            for (int cf = 0; cf < 4; ++cf) {
                int row = m0 + wr * 64 + fr * 16 + g * 4;
                int b = row >> 11, s = row & 2047;
                int col = n0 + wc * 64 + cf * 16 + r;
                ushort4 pk;
                pk.x = f2bf(acc[fr][cf][0]); pk.y = f2bf(acc[fr][cf][1]);
                pk.z = f2bf(acc[fr][cf][2]); pk.w = f2bf(acc[fr][cf][3]);
                *(ushort4*)&O[(size_t)b * DI * SS + (size_t)col * SS + s] = pk;
            }
    }
}

// ---------------- fused causal attention -------------------------------------
// Block = one (batch, q-tile of 16 rows); 4 waves = 4 e-quarters (192 cols).
// acc[12] = 48 AGPRs/wave -> room for deep K-load pipelining; Q staged once in
// LDS (shared); K global loads identical across the 4 waves (L1 dedup).
__global__ __launch_bounds__(256, 3) void attn_kernel(
    const unsigned short* __restrict__ ws, float* __restrict__ out)
{
    __shared__ unsigned short Qs[16 * 768]; // 24 KB, XOR-swizzled rows

    const int id = blockIdx.x;
    const int b = id & 7;                 // one batch per XCD
    const int jr = id >> 3;               // 0..127
    const int j = (jr & 1) ? (127 - (jr >> 1)) : (jr >> 1); // heavy/light interleave
    const int tid = threadIdx.x;
    const int w = tid >> 6, lane = tid & 63;
    const int r = lane & 15, g = lane >> 4;
    const int q0 = j * 16;
    const int e0 = w * 192;

    const unsigned short* Qb = ws + (size_t)b * SS * DI;
    const unsigned short* Kb = ws + QK_ELEMS + (size_t)b * SS * DI;
    const unsigned short* Vb = ws + 2 * QK_ELEMS + (size_t)b * DI * SS;

    // stage Q tile: linear global read -> XOR-swizzled LDS (row&7)<<4
    #pragma unroll
    for (int i = 0; i < 6; ++i) {
        int lin = tid * 16 + i * 4096;        // byte offset in tile [0, 24576)
        int row = lin / 1536;
        s16x8 v = *(const s16x8*)((const char*)Qb + (size_t)j * 24576 + lin);
        *(s16x8*)((char*)Qs + (lin ^ ((row & 7) << 4))) = v;
    }
    __syncthreads();

    const int qbase = r * 1536 + g * 16;
    const int qswz = (r & 7) << 4;

    f32x4 acc[12];
    #pragma unroll
    for (int cf = 0; cf < 12; ++cf) acc[cf] = (f32x4){0.f, 0.f, 0.f, 0.f};
    float m = -1e30f, lp = 0.f;

    const int nt = q0 / 32 + 1;
    for (int kt = 0; kt < nt; ++kt) {
        const int k0 = kt * 32;
        // 4 independent accumulation chains (t even/odd x two k-row groups)
        f32x4 s0a = {0,0,0,0}, s0b = {0,0,0,0}, s1a = {0,0,0,0}, s1b = {0,0,0,0};
        #pragma unroll
        for (int t = 0; t < 24; t += 2) {
            s16x8 q0f = *(const s16x8*)((const char*)Qs + ((qbase + t * 64) ^ qswz));
            s16x8 q1f = *(const s16x8*)((const char*)Qs + ((qbase + t * 64 + 64) ^ qswz));
            s16x8 a00 = *(const s16x8*)(Kb + (size_t)(k0 + r) * DI + t * 32 + g * 8);
            s16x8 a01 = *(const s16x8*)(Kb + (size_t)(k0 + 16 + r) * DI + t * 32 + g * 8);
            s16x8 a10 = *(const s16x8*)(Kb + (size_t)(k0 + r) * DI + t * 32 + 32 + g * 8);
            s16x8 a11 = *(const s16x8*)(Kb + (size_t)(k0 + 16 + r) * DI + t * 32 + 32 + g * 8);
            s0a = __builtin_amdgcn_mfma_f32_16x16x32_bf16(a00, q0f, s0a, 0, 0, 0);
            s1a = __builtin_amdgcn_mfma_f32_16x16x32_bf16(a01, q0f, s1a, 0, 0, 0);
            s0b = __builtin_amdgcn_mfma_f32_16x16x32_bf16(a10, q1f, s0b, 0, 0, 0);
            s1b = __builtin_amdgcn_mfma_f32_16x16x32_bf16(a11, q1f, s1b, 0, 0, 0);
        }
        f32x4 s0, s1;
        #pragma unroll
        for (int jj = 0; jj < 4; ++jj) { s0[jj] = s0a[jj] + s0b[jj]; s1[jj] = s1a[jj] + s1b[jj]; }

        if (k0 + 31 > q0) {
            #pragma unroll
            for (int jj = 0; jj < 4; ++jj) {
                if (k0 + 4 * g + jj > q0 + r)      s0[jj] = -1e30f;
                if (k0 + 16 + 4 * g + jj > q0 + r) s1[jj] = -1e30f;
            }
        }
        float v = s0[0];
        #pragma unroll
        for (int jj = 1; jj < 4; ++jj) v = fmaxf(v, s0[jj]);
        #pragma unroll
        for (int jj = 0; jj < 4; ++jj) v = fmaxf(v, s1[jj]);
        v = fmaxf(v, __shfl_xor(v, 16));
        v = fmaxf(v, __shfl_xor(v, 32));
        if (__any(v > m + 8.0f)) {               // deferred rescale (THR=8)
            const float mn = fmaxf(m, v);
            const float alpha = __expf(m - mn);
            m = mn;
            lp *= alpha;
            float al[4];
            #pragma unroll
            for (int jj = 0; jj < 4; ++jj) al[jj] = __shfl(alpha, 4 * g + jj);
            #pragma unroll
            for (int cf = 0; cf < 12; ++cf)
                #pragma unroll
                for (int jj = 0; jj < 4; ++jj) acc[cf][jj] *= al[jj];
        }
        float p0[4], p1[4];
        #pragma unroll
        for (int jj = 0; jj < 4; ++jj) {
            p0[jj] = __expf(s0[jj] - m);
            p1[jj] = __expf(s1[jj] - m);
            lp += p0[jj] + p1[jj];
        }
        s16x4 pa0, pa1;
        #pragma unroll
        for (int jj = 0; jj < 4; ++jj) {
            pa0[jj] = (short)f2bf(p0[jj]);
            pa1[jj] = (short)f2bf(p1[jj]);
        }
        #pragma unroll
        for (int cf = 0; cf < 12; ++cf) {
            const unsigned short* vrow = Vb + (size_t)(e0 + cf * 16 + r) * SS + k0;
            s16x4 vb0 = *(const s16x4*)(vrow + 4 * g);
            s16x4 vb1 = *(const s16x4*)(vrow + 16 + 4 * g);
            acc[cf] = __builtin_amdgcn_mfma_f32_16x16x16bf16_1k(pa0, vb0, acc[cf], 0, 0, 0);
            acc[cf] = __builtin_amdgcn_mfma_f32_16x16x16bf16_1k(pa1, vb1, acc[cf], 0, 0, 0);
        }
    }
    // epilogue
    lp += __shfl_xor(lp, 16);
    lp += __shfl_xor(lp, 32);
    const float linv = 1.0f / lp;
    float lv[4];
    #pragma unroll
    for (int jj = 0; jj < 4; ++jj) lv[jj] = __shfl(linv, 4 * g + jj);
    float* Ob = out + (size_t)b * SS * DI;
    #pragma unroll
    for (int cf = 0; cf < 12; ++cf)
        #pragma unroll
        for (int jj = 0; jj < 4; ++jj)
            Ob[(size_t)(q0 + 4 * g + jj) * DI + e0 + cf * 16 + r] = acc[cf][jj] * lv[jj];
}

extern "C" void kernel_launch(void* const* d_in, const int* in_sizes, int n_in,
                              void* d_out, int out_size, void* d_ws, size_t ws_size,
                              hipStream_t stream) {
    const float* x  = (const float*)d_in[0];
    const float* wq = (const float*)d_in[1];
    const float* wk = (const float*)d_in[2];
    const float* wv = (const float*)d_in[3];
    unsigned short* ws = (unsigned short*)d_ws;
    float* out = (float*)d_out;

    proj_kernel<<<dim3(6, 128, 3), 256, 0, stream>>>(x, wq, wk, wv, ws);
    attn_kernel<<<1024, 256, 0, stream>>>(ws, out);
}

// Round 4
// 831.169 us; speedup vs baseline: 2.3799x; 2.3799x over previous
//
#include <hip/hip_runtime.h>
#include <hip/hip_bf16.h>

#define DI 768
#define SS 2048
#define QK_ELEMS ((size_t)16384 * 768)

typedef float f32x4 __attribute__((ext_vector_type(4)));
typedef short s16x8 __attribute__((ext_vector_type(8)));
typedef short s16x4 __attribute__((ext_vector_type(4)));

static __device__ __forceinline__ unsigned short f2bf(float f) {
    union { float f; unsigned int u; } a; a.f = f;
    unsigned int r = (a.u + 0x7FFFu + ((a.u >> 16) & 1u)) >> 16; // RNE
    return (unsigned short)r;
}

#define GLOAD_LDS16(SRC, DST) \
    __builtin_amdgcn_global_load_lds((const __attribute__((address_space(1))) unsigned int*)(SRC), \
                                     (__attribute__((address_space(3))) unsigned int*)(DST), 16, 0, 0)

// ---------------- projection: Q = x@wq (pre-scaled), K = x@wk (PRE-SWIZZLED),
//                  Vt = (x@wv)^T --------------------------------------------
// K is stored with col ^= ((row&7)<<3) so the attn kernel can stage it into
// LDS linearly via global_load_lds and read fragments conflict-free.
__global__ __launch_bounds__(256) void proj_kernel(
    const float* __restrict__ x, const float* __restrict__ wq,
    const float* __restrict__ wk, const float* __restrict__ wv,
    unsigned short* __restrict__ ws)
{
    constexpr int LDT = 40;
    __shared__ unsigned short As[128 * LDT];
    __shared__ unsigned short Bs[128 * LDT];

    const int which = blockIdx.z;
    const float* w = (which == 0) ? wq : (which == 1) ? wk : wv;
    const int n0 = blockIdx.x * 128;
    const int m0 = blockIdx.y * 128;
    const int tid = threadIdx.x;
    const int lane = tid & 63, wid = tid >> 6;
    const int wr = wid >> 1, wc = wid & 1;
    const int r = lane & 15, g = lane >> 4;

    f32x4 acc[4][4];
    #pragma unroll
    for (int i = 0; i < 4; ++i)
        #pragma unroll
        for (int j = 0; j < 4; ++j) acc[i][j] = (f32x4){0.f, 0.f, 0.f, 0.f};

    for (int k0 = 0; k0 < DI; k0 += 32) {
        #pragma unroll
        for (int i = 0; i < 4; ++i) {
            int idx = tid + i * 256;
            int row = idx >> 3, c4 = (idx & 7) * 4;
            const float4 v = *(const float4*)(x + (size_t)(m0 + row) * DI + k0 + c4);
            ushort4 pk; pk.x = f2bf(v.x); pk.y = f2bf(v.y); pk.z = f2bf(v.z); pk.w = f2bf(v.w);
            *(ushort4*)&As[row * LDT + c4] = pk;
        }
        #pragma unroll
        for (int i = 0; i < 4; ++i) {
            int idx = tid + i * 256;
            int nn = (idx & 31) * 4, kk = idx >> 5;
            const float4 v = *(const float4*)(w + (size_t)(k0 + kk) * DI + n0 + nn);
            Bs[(nn + 0) * LDT + kk] = f2bf(v.x);
            Bs[(nn + 1) * LDT + kk] = f2bf(v.y);
            Bs[(nn + 2) * LDT + kk] = f2bf(v.z);
            Bs[(nn + 3) * LDT + kk] = f2bf(v.w);
        }
        __syncthreads();
        s16x8 af[4], bfr[4];
        #pragma unroll
        for (int fr = 0; fr < 4; ++fr)
            af[fr] = *(const s16x8*)&As[(wr * 64 + fr * 16 + r) * LDT + g * 8];
        #pragma unroll
        for (int cf = 0; cf < 4; ++cf)
            bfr[cf] = *(const s16x8*)&Bs[(wc * 64 + cf * 16 + r) * LDT + g * 8];
        #pragma unroll
        for (int fr = 0; fr < 4; ++fr)
            #pragma unroll
            for (int cf = 0; cf < 4; ++cf)
                acc[fr][cf] = __builtin_amdgcn_mfma_f32_16x16x32_bf16(af[fr], bfr[cf], acc[fr][cf], 0, 0, 0);
        __syncthreads();
    }

    const float scale = (which == 0) ? 0.03608439182435161f : 1.0f;
    if (which < 2) {
        unsigned short* O = ws + (size_t)which * QK_ELEMS;
        #pragma unroll
        for (int fr = 0; fr < 4; ++fr)
            #pragma unroll
            for (int cf = 0; cf < 4; ++cf) {
                int row = m0 + wr * 64 + fr * 16 + g * 4;
                int col = n0 + wc * 64 + cf * 16 + r;
                #pragma unroll
                for (int jj = 0; jj < 4; ++jj) {
                    int rr = row + jj;
                    int cc = (which == 1) ? (col ^ ((rr & 7) << 3)) : col; // K pre-swizzle
                    O[(size_t)rr * DI + cc] = f2bf(acc[fr][cf][jj] * scale);
                }
            }
    } else {
        unsigned short* O = ws + 2 * QK_ELEMS; // Vt[b][e][s], plain
        #pragma unroll
        for (int fr = 0; fr < 4; ++fr)
            #pragma unroll
            for (int cf = 0; cf < 4; ++cf) {
                int row = m0 + wr * 64 + fr * 16 + g * 4;
                int b = row >> 11, s = row & 2047;
                int col = n0 + wc * 64 + cf * 16 + r;
                ushort4 pk;
                pk.x = f2bf(acc[fr][cf][0]); pk.y = f2bf(acc[fr][cf][1]);
                pk.z = f2bf(acc[fr][cf][2]); pk.w = f2bf(acc[fr][cf][3]);
                *(ushort4*)&O[(size_t)b * DI * SS + (size_t)col * SS + s] = pk;
            }
    }
}

// ---------------- fused causal attention -------------------------------------
// Block = (batch, jp); two sequential passes j=jp then j=127-jp (65 tiles
// total, balanced). 4 waves split e into quarters; K tile (32x768, 48KB)
// staged cooperatively via global_load_lds (no dest VGPRs -> deep overlap),
// conflict-free swizzled ds_read. Q in registers; V direct global loads.
__global__ __launch_bounds__(256, 1) void attn_kernel(
    const unsigned short* __restrict__ ws, float* __restrict__ out)
{
    __shared__ unsigned short Ks[32 * 768]; // 48KB

    const int id = blockIdx.x;
    const int b = id & 7;                  // one batch per XCD
    const int jp = id >> 3;                // 0..63
    const int tid = threadIdx.x;
    const int w = tid >> 6, lane = tid & 63;
    const int r = lane & 15, g = lane >> 4;
    const int e0 = w * 192;

    const unsigned short* Qb = ws + (size_t)b * SS * DI;
    const unsigned short* Kb = ws + QK_ELEMS + (size_t)b * SS * DI;   // swizzled
    const unsigned short* Vb = ws + 2 * QK_ELEMS + (size_t)b * DI * SS;

    const int swz = (r & 7) << 4;          // byte swizzle for K fragment reads
    const char* KsB = (const char*)Ks;

    for (int pass = 0; pass < 2; ++pass) {
        const int j = pass ? (127 - jp) : jp;
        const int q0 = j * 16;

        // resident Q fragments: lane holds row q0+r
        s16x8 qf[24];
        #pragma unroll
        for (int t = 0; t < 24; ++t)
            qf[t] = *(const s16x8*)(Qb + (size_t)(q0 + r) * DI + t * 32 + g * 8);

        f32x4 acc[12];
        #pragma unroll
        for (int cf = 0; cf < 12; ++cf) acc[cf] = (f32x4){0.f, 0.f, 0.f, 0.f};
        float m = -1e30f, lp = 0.f;

        const int nt = q0 / 32 + 1;
        for (int kt = 0; kt < nt; ++kt) {
            const int k0 = kt * 32;
            // cooperative stage: 48 x 1KB, 12 per wave, linear dest
            #pragma unroll
            for (int i = 0; i < 12; ++i) {
                const int idx = w * 12 + i;
                GLOAD_LDS16(Kb + (size_t)k0 * DI + idx * 512 + lane * 8, &Ks[idx * 512]);
            }
            __syncthreads();   // vmcnt(0) drain: K tile ready

            f32x4 s0a = {0,0,0,0}, s0b = {0,0,0,0}, s1a = {0,0,0,0}, s1b = {0,0,0,0};
            #pragma unroll
            for (int t = 0; t < 24; t += 2) {
                const int c0 = (t * 64 + g * 16) ^ swz;
                const int c1 = (t * 64 + 64 + g * 16) ^ swz;
                s16x8 a00 = *(const s16x8*)(KsB + r * 1536 + c0);
                s16x8 a01 = *(const s16x8*)(KsB + (r + 16) * 1536 + c0);
                s16x8 a10 = *(const s16x8*)(KsB + r * 1536 + c1);
                s16x8 a11 = *(const s16x8*)(KsB + (r + 16) * 1536 + c1);
                s0a = __builtin_amdgcn_mfma_f32_16x16x32_bf16(a00, qf[t],     s0a, 0, 0, 0);
                s1a = __builtin_amdgcn_mfma_f32_16x16x32_bf16(a01, qf[t],     s1a, 0, 0, 0);
                s0b = __builtin_amdgcn_mfma_f32_16x16x32_bf16(a10, qf[t + 1], s0b, 0, 0, 0);
                s1b = __builtin_amdgcn_mfma_f32_16x16x32_bf16(a11, qf[t + 1], s1b, 0, 0, 0);
            }
            f32x4 s0, s1;
            #pragma unroll
            for (int jj = 0; jj < 4; ++jj) { s0[jj] = s0a[jj] + s0b[jj]; s1[jj] = s1a[jj] + s1b[jj]; }

            if (k0 + 31 > q0) {
                #pragma unroll
                for (int jj = 0; jj < 4; ++jj) {
                    if (k0 + 4 * g + jj > q0 + r)      s0[jj] = -1e30f;
                    if (k0 + 16 + 4 * g + jj > q0 + r) s1[jj] = -1e30f;
                }
            }
            float v = s0[0];
            #pragma unroll
            for (int jj = 1; jj < 4; ++jj) v = fmaxf(v, s0[jj]);
            #pragma unroll
            for (int jj = 0; jj < 4; ++jj) v = fmaxf(v, s1[jj]);
            v = fmaxf(v, __shfl_xor(v, 16));
            v = fmaxf(v, __shfl_xor(v, 32));
            if (__any(v > m + 8.0f)) {               // deferred rescale (THR=8)
                const float mn = fmaxf(m, v);
                const float alpha = __expf(m - mn);
                m = mn;
                lp *= alpha;
                float al[4];
                #pragma unroll
                for (int jj = 0; jj < 4; ++jj) al[jj] = __shfl(alpha, 4 * g + jj);
                #pragma unroll
                for (int cf = 0; cf < 12; ++cf)
                    #pragma unroll
                    for (int jj = 0; jj < 4; ++jj) acc[cf][jj] *= al[jj];
            }
            float p0[4], p1[4];
            #pragma unroll
            for (int jj = 0; jj < 4; ++jj) {
                p0[jj] = __expf(s0[jj] - m);
                p1[jj] = __expf(s1[jj] - m);
                lp += p0[jj] + p1[jj];
            }
            s16x4 pa0, pa1;
            #pragma unroll
            for (int jj = 0; jj < 4; ++jj) {
                pa0[jj] = (short)f2bf(p0[jj]);
                pa1[jj] = (short)f2bf(p1[jj]);
            }
            #pragma unroll
            for (int cf = 0; cf < 12; ++cf) {
                const unsigned short* vrow = Vb + (size_t)(e0 + cf * 16 + r) * SS + k0;
                s16x4 vb0 = *(const s16x4*)(vrow + 4 * g);
                s16x4 vb1 = *(const s16x4*)(vrow + 16 + 4 * g);
                acc[cf] = __builtin_amdgcn_mfma_f32_16x16x16bf16_1k(pa0, vb0, acc[cf], 0, 0, 0);
                acc[cf] = __builtin_amdgcn_mfma_f32_16x16x16bf16_1k(pa1, vb1, acc[cf], 0, 0, 0);
            }
            __syncthreads();   // protect Ks before next stage
        }
        // epilogue
        lp += __shfl_xor(lp, 16);
        lp += __shfl_xor(lp, 32);
        const float linv = 1.0f / lp;
        float lv[4];
        #pragma unroll
        for (int jj = 0; jj < 4; ++jj) lv[jj] = __shfl(linv, 4 * g + jj);
        float* Ob = out + (size_t)b * SS * DI;
        #pragma unroll
        for (int cf = 0; cf < 12; ++cf)
            #pragma unroll
            for (int jj = 0; jj < 4; ++jj)
                Ob[(size_t)(q0 + 4 * g + jj) * DI + e0 + cf * 16 + r] = acc[cf][jj] * lv[jj];
    }
}

extern "C" void kernel_launch(void* const* d_in, const int* in_sizes, int n_in,
                              void* d_out, int out_size, void* d_ws, size_t ws_size,
                              hipStream_t stream) {
    const float* x  = (const float*)d_in[0];
    const float* wq = (const float*)d_in[1];
    const float* wk = (const float*)d_in[2];
    const float* wv = (const float*)d_in[3];
    unsigned short* ws = (unsigned short*)d_ws;
    float* out = (float*)d_out;

    proj_kernel<<<dim3(6, 128, 3), 256, 0, stream>>>(x, wq, wk, wv, ws);
    attn_kernel<<<512, 256, 0, stream>>>(ws, out);
}

// Round 5
// 611.128 us; speedup vs baseline: 3.2368x; 1.3601x over previous
//
#include <hip/hip_runtime.h>
#include <hip/hip_bf16.h>

#define DI 768
#define SS 2048
#define QK_ELEMS ((size_t)16384 * 768)

typedef float f32x4 __attribute__((ext_vector_type(4)));
typedef short s16x8 __attribute__((ext_vector_type(8)));
typedef short s16x4 __attribute__((ext_vector_type(4)));

static __device__ __forceinline__ unsigned short f2bf(float f) {
    union { float f; unsigned int u; } a; a.f = f;
    unsigned int r = (a.u + 0x7FFFu + ((a.u >> 16) & 1u)) >> 16; // RNE
    return (unsigned short)r;
}

#define GLOAD_LDS16(SRC, DST) \
    __builtin_amdgcn_global_load_lds((const __attribute__((address_space(1))) unsigned int*)(SRC), \
                                     (__attribute__((address_space(3))) unsigned int*)(DST), 16, 0, 0)

// ---------------- projection: Q = x@wq (pre-scaled), K = x@wk (PRE-SWIZZLED),
//                  Vt = (x@wv)^T --------------------------------------------
__global__ __launch_bounds__(256) void proj_kernel(
    const float* __restrict__ x, const float* __restrict__ wq,
    const float* __restrict__ wk, const float* __restrict__ wv,
    unsigned short* __restrict__ ws)
{
    constexpr int LDT = 40;
    __shared__ unsigned short As[128 * LDT];
    __shared__ unsigned short Bs[128 * LDT];

    const int which = blockIdx.z;
    const float* w = (which == 0) ? wq : (which == 1) ? wk : wv;
    const int n0 = blockIdx.x * 128;
    const int m0 = blockIdx.y * 128;
    const int tid = threadIdx.x;
    const int lane = tid & 63, wid = tid >> 6;
    const int wr = wid >> 1, wc = wid & 1;
    const int r = lane & 15, g = lane >> 4;

    f32x4 acc[4][4];
    #pragma unroll
    for (int i = 0; i < 4; ++i)
        #pragma unroll
        for (int j = 0; j < 4; ++j) acc[i][j] = (f32x4){0.f, 0.f, 0.f, 0.f};

    for (int k0 = 0; k0 < DI; k0 += 32) {
        #pragma unroll
        for (int i = 0; i < 4; ++i) {
            int idx = tid + i * 256;
            int row = idx >> 3, c4 = (idx & 7) * 4;
            const float4 v = *(const float4*)(x + (size_t)(m0 + row) * DI + k0 + c4);
            ushort4 pk; pk.x = f2bf(v.x); pk.y = f2bf(v.y); pk.z = f2bf(v.z); pk.w = f2bf(v.w);
            *(ushort4*)&As[row * LDT + c4] = pk;
        }
        {   // B transposed, vectorized: Bs[n][k] = w[k0+k][n0+n]
            const int kq = (tid >> 5) * 4;
            const int nq = (tid & 31) * 4;
            float va[4][4];
            #pragma unroll
            for (int d = 0; d < 4; ++d)
                *(float4*)va[d] = *(const float4*)(w + (size_t)(k0 + kq + d) * DI + n0 + nq);
            #pragma unroll
            for (int i2 = 0; i2 < 4; ++i2) {
                ushort4 u;
                u.x = f2bf(va[0][i2]); u.y = f2bf(va[1][i2]);
                u.z = f2bf(va[2][i2]); u.w = f2bf(va[3][i2]);
                *(ushort4*)&Bs[(nq + i2) * LDT + kq] = u;
            }
        }
        __syncthreads();
        s16x8 af[4], bfr[4];
        #pragma unroll
        for (int fr = 0; fr < 4; ++fr)
            af[fr] = *(const s16x8*)&As[(wr * 64 + fr * 16 + r) * LDT + g * 8];
        #pragma unroll
        for (int cf = 0; cf < 4; ++cf)
            bfr[cf] = *(const s16x8*)&Bs[(wc * 64 + cf * 16 + r) * LDT + g * 8];
        #pragma unroll
        for (int fr = 0; fr < 4; ++fr)
            #pragma unroll
            for (int cf = 0; cf < 4; ++cf)
                acc[fr][cf] = __builtin_amdgcn_mfma_f32_16x16x32_bf16(af[fr], bfr[cf], acc[fr][cf], 0, 0, 0);
        __syncthreads();
    }

    const float scale = (which == 0) ? 0.03608439182435161f : 1.0f;
    if (which < 2) {
        unsigned short* O = ws + (size_t)which * QK_ELEMS;
        #pragma unroll
        for (int fr = 0; fr < 4; ++fr)
            #pragma unroll
            for (int cf = 0; cf < 4; ++cf) {
                int row = m0 + wr * 64 + fr * 16 + g * 4;
                int col = n0 + wc * 64 + cf * 16 + r;
                #pragma unroll
                for (int jj = 0; jj < 4; ++jj) {
                    int rr = row + jj;
                    int cc = (which == 1) ? (col ^ ((rr & 7) << 3)) : col; // K pre-swizzle
                    O[(size_t)rr * DI + cc] = f2bf(acc[fr][cf][jj] * scale);
                }
            }
    } else {
        unsigned short* O = ws + 2 * QK_ELEMS; // Vt[b][e][s]
        #pragma unroll
        for (int fr = 0; fr < 4; ++fr)
            #pragma unroll
            for (int cf = 0; cf < 4; ++cf) {
                int row = m0 + wr * 64 + fr * 16 + g * 4;
                int b = row >> 11, s = row & 2047;
                int col = n0 + wc * 64 + cf * 16 + r;
                ushort4 pk;
                pk.x = f2bf(acc[fr][cf][0]); pk.y = f2bf(acc[fr][cf][1]);
                pk.z = f2bf(acc[fr][cf][2]); pk.w = f2bf(acc[fr][cf][3]);
                *(ushort4*)&O[(size_t)b * DI * SS + (size_t)col * SS + s] = pk;
            }
    }
}

// ---------------- fused causal attention -------------------------------------
// 512 threads = 8 waves. Block owns a PAIR of q-tiles (jbase, jbase+1), two
// sequential pair-passes (2a,2a+1) then (126-2a,127-2a) -> equal work/block.
// KVBLK=64 staged ONCE per block via global_load_lds; wave (qsel,wv): q-tile
// qsel, k-slice wv (16 rows, no QK duplication) and e-quarter wv for PV.
// Softmax shared via tiny LDS exchanges; next-tile stage overlaps softmax+PV
// (raw barrier C has NO vmcnt drain).
__global__ __launch_bounds__(512, 2) void attn_kernel(
    const unsigned short* __restrict__ ws, float* __restrict__ out)
{
    __shared__ unsigned short Ks[64 * 768];     // 96 KB
    __shared__ unsigned short P_lds[2048];      // [qsel][slice][16q][16k] bf16, 4 KB
    __shared__ float redm[128];                 // [qsel][slice][16q] partials

    const int id = blockIdx.x;
    const int b = id & 7;                  // one batch per XCD
    const int a = id >> 3;                 // 0..31
    const int tid = threadIdx.x;
    const int wid = tid >> 6, lane = tid & 63;
    const int qsel = wid >> 2;             // which q-tile of the pair
    const int wv = wid & 3;                // k-slice owner & e-quarter owner
    const int r = lane & 15, g = lane >> 4;
    const int e0 = wv * 192;
    const int rw = wv * 16 + r;            // K LDS row for QK A-frag
    const int swz = (r & 7) << 4;

    const unsigned short* Qb = ws + (size_t)b * SS * DI;
    const unsigned short* Kb = ws + QK_ELEMS + (size_t)b * SS * DI;   // pre-swizzled
    const unsigned short* Vb = ws + 2 * QK_ELEMS + (size_t)b * DI * SS;
    float* Ob = out + (size_t)b * SS * DI;
    const char* KsB = (const char*)Ks;

#define STAGEK(KT) do { \
        const size_t sbase_ = (size_t)(KT) * 64 * DI; \
        _Pragma("unroll") \
        for (int i_ = 0; i_ < 12; ++i_) { \
            const int idx_ = wid * 12 + i_; \
            GLOAD_LDS16(Kb + sbase_ + idx_ * 512 + lane * 8, &Ks[idx_ * 512]); \
        } \
    } while (0)

    for (int pp = 0; pp < 2; ++pp) {
        const int jbase = pp ? (126 - 2 * a) : (2 * a);
        const int j = jbase + qsel;
        const int q0 = j * 16;
        const int nt_own = (q0 + 79) >> 6;
        const int ntmax = (16 * (jbase + 1) + 79) >> 6;

        s16x8 qf[24];
        #pragma unroll
        for (int t = 0; t < 24; ++t)
            qf[t] = *(const s16x8*)(Qb + (size_t)(q0 + r) * DI + t * 32 + g * 8);

        f32x4 acc[12];
        #pragma unroll
        for (int cf = 0; cf < 12; ++cf) acc[cf] = (f32x4){0.f, 0.f, 0.f, 0.f};
        float m = -1e30f, lp = 0.f;

        STAGEK(0);

        for (int kt = 0; kt < ntmax; ++kt) {
            const int k0 = kt * 64;
            const bool act = kt < nt_own;
            __syncthreads();                        // A: K tile staged (vmcnt drain)

            f32x4 s = {0.f, 0.f, 0.f, 0.f};
            if (act) {
                f32x4 sa = {0,0,0,0}, sb = {0,0,0,0};
                #pragma unroll
                for (int t = 0; t < 24; t += 2) {
                    s16x8 k0f = *(const s16x8*)(KsB + rw * 1536 + ((t * 64 + g * 16) ^ swz));
                    s16x8 k1f = *(const s16x8*)(KsB + rw * 1536 + (((t + 1) * 64 + g * 16) ^ swz));
                    sa = __builtin_amdgcn_mfma_f32_16x16x32_bf16(k0f, qf[t],     sa, 0, 0, 0);
                    sb = __builtin_amdgcn_mfma_f32_16x16x32_bf16(k1f, qf[t + 1], sb, 0, 0, 0);
                }
                #pragma unroll
                for (int jj = 0; jj < 4; ++jj) s[jj] = sa[jj] + sb[jj];
                if (k0 + 64 > q0) {                 // boundary: causal mask
                    #pragma unroll
                    for (int jj = 0; jj < 4; ++jj)
                        if (k0 + 16 * wv + 4 * g + jj > q0 + r) s[jj] = -1e30f;
                }
                float v = fmaxf(fmaxf(s[0], s[1]), fmaxf(s[2], s[3]));
                v = fmaxf(v, __shfl_xor(v, 16));
                v = fmaxf(v, __shfl_xor(v, 32));
                if (lane < 16) redm[qsel * 64 + wv * 16 + lane] = v;
            }
            __syncthreads();                        // B: maxes ready, K consumed

            if (kt + 1 < ntmax) STAGEK(kt + 1);     // overlap with softmax + PV

            if (act) {
                const float* rq = &redm[qsel * 64];
                float vmax = fmaxf(fmaxf(rq[r], rq[16 + r]), fmaxf(rq[32 + r], rq[48 + r]));
                if (__any(vmax > m + 8.0f)) {       // deferred rescale (THR=8)
                    const float mn = fmaxf(m, vmax);
                    const float alpha = __expf(m - mn);
                    m = mn;
                    lp *= alpha;
                    float al[4];
                    #pragma unroll
                    for (int jj = 0; jj < 4; ++jj) al[jj] = __shfl(alpha, 4 * g + jj);
                    #pragma unroll
                    for (int cf = 0; cf < 12; ++cf)
                        #pragma unroll
                        for (int jj = 0; jj < 4; ++jj) acc[cf][jj] *= al[jj];
                }
                s16x4 pw;
                #pragma unroll
                for (int jj = 0; jj < 4; ++jj) {
                    float p = __expf(s[jj] - m);
                    lp += p;
                    pw[jj] = (short)f2bf(p);
                }
                *(s16x4*)&P_lds[qsel * 1024 + wv * 256 + r * 16 + g * 4] = pw;
            }
            // C: raw barrier, lgkm-only drain (staged K stays in flight!)
            asm volatile("s_waitcnt lgkmcnt(0)" ::: "memory");
            __builtin_amdgcn_sched_barrier(0);
            __builtin_amdgcn_s_barrier();
            __builtin_amdgcn_sched_barrier(0);

            if (act) {
                s16x4 pa[4];
                #pragma unroll
                for (int ks = 0; ks < 4; ++ks)
                    pa[ks] = *(const s16x4*)&P_lds[qsel * 1024 + ks * 256 + r * 16 + g * 4];
                #pragma unroll
                for (int cf = 0; cf < 12; ++cf) {
                    const unsigned short* vrow = Vb + (size_t)(e0 + cf * 16 + r) * SS + k0;
                    #pragma unroll
                    for (int ks = 0; ks < 4; ++ks) {
                        s16x4 vb = *(const s16x4*)(vrow + ks * 16 + 4 * g);
                        acc[cf] = __builtin_amdgcn_mfma_f32_16x16x16bf16_1k(pa[ks], vb, acc[cf], 0, 0, 0);
                    }
                }
            }
        }
        // epilogue: combine per-slice lp, normalize, store
        lp += __shfl_xor(lp, 16);
        lp += __shfl_xor(lp, 32);
        if (lane < 16) redm[qsel * 64 + wv * 16 + lane] = lp;
        __syncthreads();
        const float* rq = &redm[qsel * 64];
        const float lt = rq[r] + rq[16 + r] + rq[32 + r] + rq[48 + r];
        const float linv = 1.0f / lt;
        float lv[4];
        #pragma unroll
        for (int jj = 0; jj < 4; ++jj) lv[jj] = __shfl(linv, 4 * g + jj);
        #pragma unroll
        for (int cf = 0; cf < 12; ++cf)
            #pragma unroll
            for (int jj = 0; jj < 4; ++jj)
                Ob[(size_t)(q0 + 4 * g + jj) * DI + e0 + cf * 16 + r] = acc[cf][jj] * lv[jj];
    }
#undef STAGEK
}

extern "C" void kernel_launch(void* const* d_in, const int* in_sizes, int n_in,
                              void* d_out, int out_size, void* d_ws, size_t ws_size,
                              hipStream_t stream) {
    const float* x  = (const float*)d_in[0];
    const float* wq = (const float*)d_in[1];
    const float* wk = (const float*)d_in[2];
    const float* wv = (const float*)d_in[3];
    unsigned short* ws = (unsigned short*)d_ws;
    float* out = (float*)d_out;

    proj_kernel<<<dim3(6, 128, 3), 256, 0, stream>>>(x, wq, wk, wv, ws);
    attn_kernel<<<256, 512, 0, stream>>>(ws, out);
}

// Round 6
// 579.242 us; speedup vs baseline: 3.4149x; 1.0550x over previous
//
#include <hip/hip_runtime.h>
#include <hip/hip_bf16.h>

#define DI 768
#define SS 2048
#define QK_ELEMS ((size_t)16384 * 768)

typedef float f32x4 __attribute__((ext_vector_type(4)));
typedef short s16x8 __attribute__((ext_vector_type(8)));
typedef short s16x4 __attribute__((ext_vector_type(4)));

static __device__ __forceinline__ unsigned short f2bf(float f) {
    union { float f; unsigned int u; } a; a.f = f;
    unsigned int r = (a.u + 0x7FFFu + ((a.u >> 16) & 1u)) >> 16; // RNE
    return (unsigned short)r;
}

#define GLOAD_LDS16(SRC, DST) \
    __builtin_amdgcn_global_load_lds((const __attribute__((address_space(1))) unsigned int*)(SRC), \
                                     (__attribute__((address_space(3))) unsigned int*)(DST), 16, 0, 0)

// ---------------- projection ------------------------------------------------
// Q = x@wq (pre-scaled by 1/sqrt(768)), K = x@wk PRE-SWIZZLED (col ^= (row&7)<<3),
// V = x@wv stored FRAGMENT-PACKED: Vf[b][s/16][e/16][lane][4slot], lane =
// (e%16)+16*((s%16)>>2), slot = s%4  ->  proj C-write AND attn B-read are both
// single fully-coalesced 512B accesses per 16x16 tile.
__global__ __launch_bounds__(256) void proj_kernel(
    const float* __restrict__ x, const float* __restrict__ wq,
    const float* __restrict__ wk, const float* __restrict__ wv,
    unsigned short* __restrict__ ws)
{
    constexpr int LDT = 40;
    __shared__ unsigned short As[128 * LDT];
    __shared__ unsigned short Bs[128 * LDT];

    const int which = blockIdx.z;
    const float* w = (which == 0) ? wq : (which == 1) ? wk : wv;
    const int n0 = blockIdx.x * 128;
    const int m0 = blockIdx.y * 128;
    const int tid = threadIdx.x;
    const int lane = tid & 63, wid = tid >> 6;
    const int wr = wid >> 1, wc = wid & 1;
    const int r = lane & 15, g = lane >> 4;

    f32x4 acc[4][4];
    #pragma unroll
    for (int i = 0; i < 4; ++i)
        #pragma unroll
        for (int j = 0; j < 4; ++j) acc[i][j] = (f32x4){0.f, 0.f, 0.f, 0.f};

    for (int k0 = 0; k0 < DI; k0 += 32) {
        #pragma unroll
        for (int i = 0; i < 4; ++i) {
            int idx = tid + i * 256;
            int row = idx >> 3, c4 = (idx & 7) * 4;
            const float4 v = *(const float4*)(x + (size_t)(m0 + row) * DI + k0 + c4);
            ushort4 pk; pk.x = f2bf(v.x); pk.y = f2bf(v.y); pk.z = f2bf(v.z); pk.w = f2bf(v.w);
            *(ushort4*)&As[row * LDT + c4] = pk;
        }
        {   // B transposed, vectorized: Bs[n][k] = w[k0+k][n0+n]
            const int kq = (tid >> 5) * 4;
            const int nq = (tid & 31) * 4;
            float va[4][4];
            #pragma unroll
            for (int d = 0; d < 4; ++d)
                *(float4*)va[d] = *(const float4*)(w + (size_t)(k0 + kq + d) * DI + n0 + nq);
            #pragma unroll
            for (int i2 = 0; i2 < 4; ++i2) {
                ushort4 u;
                u.x = f2bf(va[0][i2]); u.y = f2bf(va[1][i2]);
                u.z = f2bf(va[2][i2]); u.w = f2bf(va[3][i2]);
                *(ushort4*)&Bs[(nq + i2) * LDT + kq] = u;
            }
        }
        __syncthreads();
        s16x8 af[4], bfr[4];
        #pragma unroll
        for (int fr = 0; fr < 4; ++fr)
            af[fr] = *(const s16x8*)&As[(wr * 64 + fr * 16 + r) * LDT + g * 8];
        #pragma unroll
        for (int cf = 0; cf < 4; ++cf)
            bfr[cf] = *(const s16x8*)&Bs[(wc * 64 + cf * 16 + r) * LDT + g * 8];
        #pragma unroll
        for (int fr = 0; fr < 4; ++fr)
            #pragma unroll
            for (int cf = 0; cf < 4; ++cf)
                acc[fr][cf] = __builtin_amdgcn_mfma_f32_16x16x32_bf16(af[fr], bfr[cf], acc[fr][cf], 0, 0, 0);
        __syncthreads();
    }

    const float scale = (which == 0) ? 0.03608439182435161f : 1.0f;
    if (which < 2) {
        unsigned short* O = ws + (size_t)which * QK_ELEMS;
        #pragma unroll
        for (int fr = 0; fr < 4; ++fr)
            #pragma unroll
            for (int cf = 0; cf < 4; ++cf) {
                int row = m0 + wr * 64 + fr * 16 + g * 4;
                int col = n0 + wc * 64 + cf * 16 + r;
                #pragma unroll
                for (int jj = 0; jj < 4; ++jj) {
                    int rr = row + jj;
                    int cc = (which == 1) ? (col ^ ((rr & 7) << 3)) : col; // K pre-swizzle
                    O[(size_t)rr * DI + cc] = f2bf(acc[fr][cf][jj] * scale);
                }
            }
    } else {
        unsigned short* O = ws + 2 * QK_ELEMS; // Vf fragment-packed
        #pragma unroll
        for (int fr = 0; fr < 4; ++fr)
            #pragma unroll
            for (int cf = 0; cf < 4; ++cf) {
                int row = m0 + wr * 64 + fr * 16 + g * 4;   // = b*2048 + s (g*4+jj < 16)
                int bb = row >> 11;
                int st = (row & 2047) >> 4;
                int et = ((n0 + wc * 64) >> 4) + cf;
                ushort4 pk;
                pk.x = f2bf(acc[fr][cf][0]); pk.y = f2bf(acc[fr][cf][1]);
                pk.z = f2bf(acc[fr][cf][2]); pk.w = f2bf(acc[fr][cf][3]);
                *(ushort4*)&O[(((size_t)bb * 128 + st) * 48 + et) * 256 + lane * 4] = pk;
            }
    }
}

// ---------------- fused causal attention -------------------------------------
// 512 threads = 8 waves. Block owns a PAIR of q-tiles, two pair-passes
// (2a,2a+1) then (126-2a,127-2a). KVBLK=64 staged once/block via
// global_load_lds; wave (qsel,wv): q-tile qsel, k-slice wv (no QK dup),
// e-quarter wv for PV. V read via fragment-packed Vf (coalesced 512B loads).
__global__ __launch_bounds__(512, 1) void attn_kernel(
    const unsigned short* __restrict__ ws, float* __restrict__ out)
{
    __shared__ unsigned short Ks[64 * 768];     // 96 KB
    __shared__ unsigned short P_lds[2048];      // [qsel][slice][16q][16k] bf16
    __shared__ float redm[128];                 // [qsel][slice][16q]

    const int id = blockIdx.x;
    const int b = id & 7;                  // one batch per XCD
    const int a = id >> 3;                 // 0..31
    const int tid = threadIdx.x;
    const int wid = tid >> 6, lane = tid & 63;
    const int qsel = wid >> 2;             // which q-tile of the pair
    const int wv = wid & 3;                // k-slice & e-quarter owner
    const int r = lane & 15, g = lane >> 4;
    const int e0 = wv * 192;
    const int rw = wv * 16 + r;            // K LDS row for QK A-frag
    const int swz = (r & 7) << 4;

    const unsigned short* Qb = ws + (size_t)b * SS * DI;
    const unsigned short* Kb = ws + QK_ELEMS + (size_t)b * SS * DI;     // pre-swizzled
    const unsigned short* Vf = ws + 2 * QK_ELEMS + (size_t)b * 128 * 48 * 256;
    float* Ob = out + (size_t)b * SS * DI;
    const char* KsB = (const char*)Ks;

#define STAGEK(KT) do { \
        const size_t sbase_ = (size_t)(KT) * 64 * DI; \
        _Pragma("unroll") \
        for (int i_ = 0; i_ < 12; ++i_) { \
            const int idx_ = wid * 12 + i_; \
            GLOAD_LDS16(Kb + sbase_ + idx_ * 512 + lane * 8, &Ks[idx_ * 512]); \
        } \
    } while (0)

    for (int pp = 0; pp < 2; ++pp) {
        const int jbase = pp ? (126 - 2 * a) : (2 * a);
        const int j = jbase + qsel;
        const int q0 = j * 16;
        const int nt_own = (q0 + 79) >> 6;
        const int ntmax = (16 * (jbase + 1) + 79) >> 6;

        s16x8 qf[24];
        #pragma unroll
        for (int t = 0; t < 24; ++t)
            qf[t] = *(const s16x8*)(Qb + (size_t)(q0 + r) * DI + t * 32 + g * 8);

        f32x4 acc[12];
        #pragma unroll
        for (int cf = 0; cf < 12; ++cf) acc[cf] = (f32x4){0.f, 0.f, 0.f, 0.f};
        float m = -1e30f, lp = 0.f;

        STAGEK(0);

        for (int kt = 0; kt < ntmax; ++kt) {
            const int k0 = kt * 64;
            const bool act = kt < nt_own;
            __syncthreads();                        // A: K tile staged (vmcnt drain)

            f32x4 s = {0.f, 0.f, 0.f, 0.f};
            if (act) {
                f32x4 sa = {0,0,0,0}, sb = {0,0,0,0};
                #pragma unroll
                for (int t = 0; t < 24; t += 2) {
                    s16x8 k0f = *(const s16x8*)(KsB + rw * 1536 + ((t * 64 + g * 16) ^ swz));
                    s16x8 k1f = *(const s16x8*)(KsB + rw * 1536 + (((t + 1) * 64 + g * 16) ^ swz));
                    sa = __builtin_amdgcn_mfma_f32_16x16x32_bf16(k0f, qf[t],     sa, 0, 0, 0);
                    sb = __builtin_amdgcn_mfma_f32_16x16x32_bf16(k1f, qf[t + 1], sb, 0, 0, 0);
                }
                #pragma unroll
                for (int jj = 0; jj < 4; ++jj) s[jj] = sa[jj] + sb[jj];
                if (k0 + 64 > q0) {                 // boundary: causal mask
                    #pragma unroll
                    for (int jj = 0; jj < 4; ++jj)
                        if (k0 + 16 * wv + 4 * g + jj > q0 + r) s[jj] = -1e30f;
                }
                float v = fmaxf(fmaxf(s[0], s[1]), fmaxf(s[2], s[3]));
                v = fmaxf(v, __shfl_xor(v, 16));
                v = fmaxf(v, __shfl_xor(v, 32));
                if (lane < 16) redm[qsel * 64 + wv * 16 + lane] = v;
            }
            __syncthreads();                        // B: maxes ready, K consumed

            if (kt + 1 < ntmax) STAGEK(kt + 1);     // overlap with softmax + PV

            if (act) {
                const float* rq = &redm[qsel * 64];
                float vmax = fmaxf(fmaxf(rq[r], rq[16 + r]), fmaxf(rq[32 + r], rq[48 + r]));
                if (__any(vmax > m + 8.0f)) {       // deferred rescale (THR=8)
                    const float mn = fmaxf(m, vmax);
                    const float alpha = __expf(m - mn);
                    m = mn;
                    lp *= alpha;
                    float al[4];
                    #pragma unroll
                    for (int jj = 0; jj < 4; ++jj) al[jj] = __shfl(alpha, 4 * g + jj);
                    #pragma unroll
                    for (int cf = 0; cf < 12; ++cf)
                        #pragma unroll
                        for (int jj = 0; jj < 4; ++jj) acc[cf][jj] *= al[jj];
                }
                s16x4 pw;
                #pragma unroll
                for (int jj = 0; jj < 4; ++jj) {
                    float p = __expf(s[jj] - m);
                    lp += p;
                    pw[jj] = (short)f2bf(p);
                }
                *(s16x4*)&P_lds[qsel * 1024 + wv * 256 + r * 16 + g * 4] = pw;
            }
            // C: raw barrier, lgkm-only drain (staged K stays in flight!)
            asm volatile("s_waitcnt lgkmcnt(0)" ::: "memory");
            __builtin_amdgcn_sched_barrier(0);
            __builtin_amdgcn_s_barrier();
            __builtin_amdgcn_sched_barrier(0);

            if (act) {
                s16x4 pa[4];
                #pragma unroll
                for (int ks = 0; ks < 4; ++ks)
                    pa[ks] = *(const s16x4*)&P_lds[qsel * 1024 + ks * 256 + r * 16 + g * 4];
                // fragment-packed V: one coalesced 512B load per (ks, cf)
                const size_t vbase = ((size_t)(k0 >> 4) * 48 + (e0 >> 4)) * 256 + lane * 4;
                #pragma unroll
                for (int ks = 0; ks < 4; ++ks) {
                    const unsigned short* vp = Vf + vbase + (size_t)ks * 48 * 256;
                    #pragma unroll
                    for (int cf = 0; cf < 12; ++cf) {
                        s16x4 vb = *(const s16x4*)(vp + cf * 256);
                        acc[cf] = __builtin_amdgcn_mfma_f32_16x16x16bf16_1k(pa[ks], vb, acc[cf], 0, 0, 0);
                    }
                }
            }
        }
        // epilogue: combine per-slice lp, normalize, store
        lp += __shfl_xor(lp, 16);
        lp += __shfl_xor(lp, 32);
        if (lane < 16) redm[qsel * 64 + wv * 16 + lane] = lp;
        __syncthreads();
        const float* rq = &redm[qsel * 64];
        const float lt = rq[r] + rq[16 + r] + rq[32 + r] + rq[48 + r];
        const float linv = 1.0f / lt;
        float lv[4];
        #pragma unroll
        for (int jj = 0; jj < 4; ++jj) lv[jj] = __shfl(linv, 4 * g + jj);
        #pragma unroll
        for (int cf = 0; cf < 12; ++cf)
            #pragma unroll
            for (int jj = 0; jj < 4; ++jj)
                Ob[(size_t)(q0 + 4 * g + jj) * DI + e0 + cf * 16 + r] = acc[cf][jj] * lv[jj];
    }
#undef STAGEK
}

extern "C" void kernel_launch(void* const* d_in, const int* in_sizes, int n_in,
                              void* d_out, int out_size, void* d_ws, size_t ws_size,
                              hipStream_t stream) {
    const float* x  = (const float*)d_in[0];
    const float* wq = (const float*)d_in[1];
    const float* wk = (const float*)d_in[2];
    const float* wv = (const float*)d_in[3];
    unsigned short* ws = (unsigned short*)d_ws;
    float* out = (float*)d_out;

    proj_kernel<<<dim3(6, 128, 3), 256, 0, stream>>>(x, wq, wk, wv, ws);
    attn_kernel<<<256, 512, 0, stream>>>(ws, out);
}

// Round 7
// 344.272 us; speedup vs baseline: 5.7457x; 1.6825x over previous
//
#include <hip/hip_runtime.h>
#include <hip/hip_bf16.h>

#define DI 768
#define SS 2048
#define QK_ELEMS ((size_t)16384 * 768)

typedef float f32x4 __attribute__((ext_vector_type(4)));
typedef short s16x8 __attribute__((ext_vector_type(8)));
typedef short s16x4 __attribute__((ext_vector_type(4)));

static __device__ __forceinline__ unsigned short f2bf(float f) {
    union { float f; unsigned int u; } a; a.f = f;
    unsigned int r = (a.u + 0x7FFFu + ((a.u >> 16) & 1u)) >> 16; // RNE
    return (unsigned short)r;
}

#define GLOAD_LDS16(SRC, DST) \
    __builtin_amdgcn_global_load_lds((const __attribute__((address_space(1))) unsigned int*)(SRC), \
                                     (__attribute__((address_space(3))) unsigned int*)(DST), 16, 0, 0)

// ---------------- projection ------------------------------------------------
// Q = x@wq (pre-scaled, PRE-SWIZZLED col^=(row&7)<<3), K = x@wk (PRE-SWIZZLED),
// V = x@wv FRAGMENT-PACKED: Vf[b][s/16][e/16][lane][4slot].
__global__ __launch_bounds__(256) void proj_kernel(
    const float* __restrict__ x, const float* __restrict__ wq,
    const float* __restrict__ wk, const float* __restrict__ wv,
    unsigned short* __restrict__ ws)
{
    constexpr int LDT = 40;
    __shared__ unsigned short As[128 * LDT];
    __shared__ unsigned short Bs[128 * LDT];

    const int which = blockIdx.z;
    const float* w = (which == 0) ? wq : (which == 1) ? wk : wv;
    const int n0 = blockIdx.x * 128;
    const int m0 = blockIdx.y * 128;
    const int tid = threadIdx.x;
    const int lane = tid & 63, wid = tid >> 6;
    const int wr = wid >> 1, wc = wid & 1;
    const int r = lane & 15, g = lane >> 4;

    f32x4 acc[4][4];
    #pragma unroll
    for (int i = 0; i < 4; ++i)
        #pragma unroll
        for (int j = 0; j < 4; ++j) acc[i][j] = (f32x4){0.f, 0.f, 0.f, 0.f};

    for (int k0 = 0; k0 < DI; k0 += 32) {
        #pragma unroll
        for (int i = 0; i < 4; ++i) {
            int idx = tid + i * 256;
            int row = idx >> 3, c4 = (idx & 7) * 4;
            const float4 v = *(const float4*)(x + (size_t)(m0 + row) * DI + k0 + c4);
            ushort4 pk; pk.x = f2bf(v.x); pk.y = f2bf(v.y); pk.z = f2bf(v.z); pk.w = f2bf(v.w);
            *(ushort4*)&As[row * LDT + c4] = pk;
        }
        {   // B transposed, vectorized: Bs[n][k] = w[k0+k][n0+n]
            const int kq = (tid >> 5) * 4;
            const int nq = (tid & 31) * 4;
            float va[4][4];
            #pragma unroll
            for (int d = 0; d < 4; ++d)
                *(float4*)va[d] = *(const float4*)(w + (size_t)(k0 + kq + d) * DI + n0 + nq);
            #pragma unroll
            for (int i2 = 0; i2 < 4; ++i2) {
                ushort4 u;
                u.x = f2bf(va[0][i2]); u.y = f2bf(va[1][i2]);
                u.z = f2bf(va[2][i2]); u.w = f2bf(va[3][i2]);
                *(ushort4*)&Bs[(nq + i2) * LDT + kq] = u;
            }
        }
        __syncthreads();
        s16x8 af[4], bfr[4];
        #pragma unroll
        for (int fr = 0; fr < 4; ++fr)
            af[fr] = *(const s16x8*)&As[(wr * 64 + fr * 16 + r) * LDT + g * 8];
        #pragma unroll
        for (int cf = 0; cf < 4; ++cf)
            bfr[cf] = *(const s16x8*)&Bs[(wc * 64 + cf * 16 + r) * LDT + g * 8];
        #pragma unroll
        for (int fr = 0; fr < 4; ++fr)
            #pragma unroll
            for (int cf = 0; cf < 4; ++cf)
                acc[fr][cf] = __builtin_amdgcn_mfma_f32_16x16x32_bf16(af[fr], bfr[cf], acc[fr][cf], 0, 0, 0);
        __syncthreads();
    }

    const float scale = (which == 0) ? 0.03608439182435161f : 1.0f;
    if (which < 2) {
        unsigned short* O = ws + (size_t)which * QK_ELEMS;
        #pragma unroll
        for (int fr = 0; fr < 4; ++fr)
            #pragma unroll
            for (int cf = 0; cf < 4; ++cf) {
                int row = m0 + wr * 64 + fr * 16 + g * 4;
                int col = n0 + wc * 64 + cf * 16 + r;
                #pragma unroll
                for (int jj = 0; jj < 4; ++jj) {
                    int rr = row + jj;
                    int cc = col ^ ((rr & 7) << 3);           // Q and K pre-swizzle
                    O[(size_t)rr * DI + cc] = f2bf(acc[fr][cf][jj] * scale);
                }
            }
    } else {
        unsigned short* O = ws + 2 * QK_ELEMS; // Vf fragment-packed
        #pragma unroll
        for (int fr = 0; fr < 4; ++fr)
            #pragma unroll
            for (int cf = 0; cf < 4; ++cf) {
                int row = m0 + wr * 64 + fr * 16 + g * 4;   // = b*2048 + s
                int bb = row >> 11;
                int st = (row & 2047) >> 4;
                int et = ((n0 + wc * 64) >> 4) + cf;
                ushort4 pk;
                pk.x = f2bf(acc[fr][cf][0]); pk.y = f2bf(acc[fr][cf][1]);
                pk.z = f2bf(acc[fr][cf][2]); pk.w = f2bf(acc[fr][cf][3]);
                *(ushort4*)&O[(((size_t)bb * 128 + st) * 48 + et) * 256 + lane * 4] = pk;
            }
    }
}

// ---------------- fused causal attention -------------------------------------
// 512 threads = 8 waves; block owns q-pair (jbase, jbase+1); passes (2a,2a+1)
// then (126-2a,127-2a). K (96KB) AND Q (48KB, per pass) staged via
// global_load_lds, swizzled. V prefetched to REGISTERS at tile start (issued
// BEFORE the next-tile stage, so PV consumes at vmcnt(12), stage stays in
// flight). Barriers B and C are lgkm-only; only barrier A drains vmcnt.
__global__ __launch_bounds__(512, 1) void attn_kernel(
    const unsigned short* __restrict__ ws, float* __restrict__ out)
{
    __shared__ unsigned short Ks[64 * 768];     // 96 KB
    __shared__ unsigned short Qs[32 * 768];     // 48 KB (q-pair, swizzled)
    __shared__ unsigned short P_lds[2048];      // [qsel][slice][16q][16k]
    __shared__ float redm[128];                 // [qsel][slice][16q]

    const int id = blockIdx.x;
    const int b = id & 7;                  // one batch per XCD
    const int a = id >> 3;                 // 0..31
    const int tid = threadIdx.x;
    const int wid = tid >> 6, lane = tid & 63;
    const int qsel = wid >> 2;             // q-tile of the pair
    const int wv = wid & 3;                // k-slice & e-quarter owner
    const int r = lane & 15, g = lane >> 4;
    const int e0 = wv * 192;
    const int rw = wv * 16 + r;
    const int swz = (r & 7) << 4;

    const unsigned short* Qb = ws + (size_t)b * SS * DI;                // swizzled
    const unsigned short* Kb = ws + QK_ELEMS + (size_t)b * SS * DI;     // swizzled
    const unsigned short* Vf = ws + 2 * QK_ELEMS + (size_t)b * 128 * 48 * 256;
    float* Ob = out + (size_t)b * SS * DI;
    const char* KsB = (const char*)Ks;
    const char* QsB = (const char*)Qs;

#define STAGEK(KT) do { \
        const size_t sbase_ = (size_t)(KT) * 64 * DI; \
        _Pragma("unroll") \
        for (int i_ = 0; i_ < 12; ++i_) { \
            const int idx_ = wid * 12 + i_; \
            GLOAD_LDS16(Kb + sbase_ + idx_ * 512 + lane * 8, &Ks[idx_ * 512]); \
        } \
    } while (0)

#define RAWBAR() do { \
        asm volatile("s_waitcnt lgkmcnt(0)" ::: "memory"); \
        __builtin_amdgcn_sched_barrier(0); \
        __builtin_amdgcn_s_barrier(); \
        __builtin_amdgcn_sched_barrier(0); \
    } while (0)

    for (int pp = 0; pp < 2; ++pp) {
        const int jbase = pp ? (126 - 2 * a) : (2 * a);
        const int j = jbase + qsel;
        const int q0 = j * 16;
        const int nt_own = (q0 + 79) >> 6;
        const int ntmax = (16 * (jbase + 1) + 79) >> 6;

        // stage Q pair (flat 48KB copy; rows contiguous) + first K tile
        {
            const size_t qsb = (size_t)jbase * 16 * DI;
            #pragma unroll
            for (int i_ = 0; i_ < 6; ++i_) {
                const int idx_ = wid * 6 + i_;
                GLOAD_LDS16(Qb + qsb + idx_ * 512 + lane * 8, &Qs[idx_ * 512]);
            }
        }
        STAGEK(0);

        f32x4 acc[12];
        #pragma unroll
        for (int cf = 0; cf < 12; ++cf) acc[cf] = (f32x4){0.f, 0.f, 0.f, 0.f};
        float m = -1e30f, lp = 0.f;

        for (int kt = 0; kt < ntmax; ++kt) {
            const int k0 = kt * 64;
            const bool act = kt < nt_own;
            __syncthreads();                        // A: K(kt)+Q staged (vmcnt drain)

            f32x4 s = {0.f, 0.f, 0.f, 0.f};
            s16x4 va[4][12];
            if (act) {
                // V prefetch FIRST (before any later stage in issue order)
                const size_t vbase = ((size_t)(k0 >> 4) * 48 + (e0 >> 4)) * 256 + lane * 4;
                #pragma unroll
                for (int ks = 0; ks < 4; ++ks)
                    #pragma unroll
                    for (int cf = 0; cf < 12; ++cf)
                        va[ks][cf] = *(const s16x4*)(Vf + vbase + (size_t)ks * 48 * 256 + cf * 256);

                f32x4 sa = {0,0,0,0}, sb = {0,0,0,0};
                #pragma unroll
                for (int t = 0; t < 24; t += 2) {
                    const int c0 = (t * 64 + g * 16) ^ swz;
                    const int c1 = (t * 64 + 64 + g * 16) ^ swz;
                    s16x8 qa = *(const s16x8*)(QsB + qsel * 24576 + r * 1536 + c0);
                    s16x8 qb2 = *(const s16x8*)(QsB + qsel * 24576 + r * 1536 + c1);
                    s16x8 ka = *(const s16x8*)(KsB + rw * 1536 + c0);
                    s16x8 kb2 = *(const s16x8*)(KsB + rw * 1536 + c1);
                    sa = __builtin_amdgcn_mfma_f32_16x16x32_bf16(ka, qa, sa, 0, 0, 0);
                    sb = __builtin_amdgcn_mfma_f32_16x16x32_bf16(kb2, qb2, sb, 0, 0, 0);
                }
                #pragma unroll
                for (int jj = 0; jj < 4; ++jj) s[jj] = sa[jj] + sb[jj];
                if (k0 + 64 > q0) {                 // boundary: causal mask
                    #pragma unroll
                    for (int jj = 0; jj < 4; ++jj)
                        if (k0 + 16 * wv + 4 * g + jj > q0 + r) s[jj] = -1e30f;
                }
                float v = fmaxf(fmaxf(s[0], s[1]), fmaxf(s[2], s[3]));
                v = fmaxf(v, __shfl_xor(v, 16));
                v = fmaxf(v, __shfl_xor(v, 32));
                if (lane < 16) redm[qsel * 64 + wv * 16 + lane] = v;
            }
            RAWBAR();                               // B: maxes visible, K consumed

            if (kt + 1 < ntmax) STAGEK(kt + 1);     // flies until next barrier A

            if (act) {
                const float* rq = &redm[qsel * 64];
                float vmax = fmaxf(fmaxf(rq[r], rq[16 + r]), fmaxf(rq[32 + r], rq[48 + r]));
                if (__any(vmax > m + 8.0f)) {       // deferred rescale (THR=8)
                    const float mn = fmaxf(m, vmax);
                    const float alpha = __expf(m - mn);
                    m = mn;
                    lp *= alpha;
                    float al[4];
                    #pragma unroll
                    for (int jj = 0; jj < 4; ++jj) al[jj] = __shfl(alpha, 4 * g + jj);
                    #pragma unroll
                    for (int cf = 0; cf < 12; ++cf)
                        #pragma unroll
                        for (int jj = 0; jj < 4; ++jj) acc[cf][jj] *= al[jj];
                }
                s16x4 pw;
                #pragma unroll
                for (int jj = 0; jj < 4; ++jj) {
                    float p = __expf(s[jj] - m);
                    lp += p;
                    pw[jj] = (short)f2bf(p);
                }
                *(s16x4*)&P_lds[qsel * 1024 + wv * 256 + r * 16 + g * 4] = pw;
            }
            RAWBAR();                               // C: P ready (stage in flight)

            if (act) {
                s16x4 pa[4];
                #pragma unroll
                for (int ks = 0; ks < 4; ++ks)
                    pa[ks] = *(const s16x4*)&P_lds[qsel * 1024 + ks * 256 + r * 16 + g * 4];
                #pragma unroll
                for (int cf = 0; cf < 12; ++cf)
                    #pragma unroll
                    for (int ks = 0; ks < 4; ++ks)
                        acc[cf] = __builtin_amdgcn_mfma_f32_16x16x16bf16_1k(pa[ks], va[ks][cf], acc[cf], 0, 0, 0);
            }
        }
        // epilogue: combine per-slice lp, normalize, store
        lp += __shfl_xor(lp, 16);
        lp += __shfl_xor(lp, 32);
        if (lane < 16) redm[qsel * 64 + wv * 16 + lane] = lp;
        __syncthreads();
        const float* rq = &redm[qsel * 64];
        const float lt = rq[r] + rq[16 + r] + rq[32 + r] + rq[48 + r];
        const float linv = 1.0f / lt;
        float lv[4];
        #pragma unroll
        for (int jj = 0; jj < 4; ++jj) lv[jj] = __shfl(linv, 4 * g + jj);
        #pragma unroll
        for (int cf = 0; cf < 12; ++cf)
            #pragma unroll
            for (int jj = 0; jj < 4; ++jj)
                Ob[(size_t)(q0 + 4 * g + jj) * DI + e0 + cf * 16 + r] = acc[cf][jj] * lv[jj];
        __syncthreads();                            // Qs/P_lds safe to overwrite
    }
#undef STAGEK
#undef RAWBAR
}

extern "C" void kernel_launch(void* const* d_in, const int* in_sizes, int n_in,
                              void* d_out, int out_size, void* d_ws, size_t ws_size,
                              hipStream_t stream) {
    const float* x  = (const float*)d_in[0];
    const float* wq = (const float*)d_in[1];
    const float* wk = (const float*)d_in[2];
    const float* wv = (const float*)d_in[3];
    unsigned short* ws = (unsigned short*)d_ws;
    float* out = (float*)d_out;

    proj_kernel<<<dim3(6, 128, 3), 256, 0, stream>>>(x, wq, wk, wv, ws);
    attn_kernel<<<256, 512, 0, stream>>>(ws, out);
}

// Round 8
// 331.087 us; speedup vs baseline: 5.9745x; 1.0398x over previous
//
#include <hip/hip_runtime.h>
#include <hip/hip_bf16.h>

#define DI 768
#define SS 2048
#define QK_ELEMS ((size_t)16384 * 768)

typedef float f32x4 __attribute__((ext_vector_type(4)));
typedef short s16x8 __attribute__((ext_vector_type(8)));
typedef short s16x4 __attribute__((ext_vector_type(4)));

static __device__ __forceinline__ unsigned short f2bf(float f) {
    union { float f; unsigned int u; } a; a.f = f;
    unsigned int r = (a.u + 0x7FFFu + ((a.u >> 16) & 1u)) >> 16; // RNE
    return (unsigned short)r;
}

#define GLOAD_LDS16(SRC, DST) \
    __builtin_amdgcn_global_load_lds((const __attribute__((address_space(1))) unsigned int*)(SRC), \
                                     (__attribute__((address_space(3))) unsigned int*)(DST), 16, 0, 0)

// ---------------- x -> bf16 (stashed in d_out; attn overwrites it later) -----
__global__ __launch_bounds__(256) void conv_kernel(
    const float* __restrict__ x, unsigned short* __restrict__ xb)
{
    const size_t i = ((size_t)blockIdx.x * 256 + threadIdx.x) * 8;
    float4 a = *(const float4*)(x + i);
    float4 c = *(const float4*)(x + i + 4);
    ushort4 u0, u1;
    u0.x = f2bf(a.x); u0.y = f2bf(a.y); u0.z = f2bf(a.z); u0.w = f2bf(a.w);
    u1.x = f2bf(c.x); u1.y = f2bf(c.y); u1.z = f2bf(c.z); u1.w = f2bf(c.w);
    *(ushort4*)(xb + i) = u0;
    *(ushort4*)(xb + i + 4) = u1;
}

// ---------------- projection ------------------------------------------------
// A-tile staged DIRECTLY from bf16 xb via global_load_lds (swizzled source,
// byte ^ ((row&1)<<5)); B-tile = weight fp32->bf16 transposed convert.
// Q pre-scaled + PRE-SWIZZLED (col^=(row&7)<<3), K PRE-SWIZZLED, V frag-packed.
__global__ __launch_bounds__(256) void proj_kernel(
    const unsigned short* __restrict__ xb, const float* __restrict__ wq,
    const float* __restrict__ wk, const float* __restrict__ wv,
    unsigned short* __restrict__ ws)
{
    constexpr int LDT = 40;
    __shared__ unsigned short As[128 * 32];     // 8 KB, linear rows of 64B
    __shared__ unsigned short Bs[128 * LDT];    // 10 KB

    const int which = blockIdx.z;
    const float* w = (which == 0) ? wq : (which == 1) ? wk : wv;
    const int n0 = blockIdx.x * 128;
    const int m0 = blockIdx.y * 128;
    const int tid = threadIdx.x;
    const int lane = tid & 63, wid = tid >> 6;
    const int wr = wid >> 1, wc = wid & 1;
    const int r = lane & 15, g = lane >> 4;

    // per-lane A-stage source offset (shorts): instruction covers 16 rows
    const int arow_l = lane >> 2;               // row within 16-row chunk
    const int aoff_l = ((lane & 3) * 16) ^ ((arow_l & 1) << 5);  // byte, swizzled
    const int asrc_l = aoff_l >> 1;             // shorts

    f32x4 acc[4][4];
    #pragma unroll
    for (int i = 0; i < 4; ++i)
        #pragma unroll
        for (int j = 0; j < 4; ++j) acc[i][j] = (f32x4){0.f, 0.f, 0.f, 0.f};

    for (int k0 = 0; k0 < DI; k0 += 32) {
        // stage A: 8 x 1KB global_load_lds, 2 per wave
        #pragma unroll
        for (int ii = 0; ii < 2; ++ii) {
            const int idx = wid * 2 + ii;       // 16-row chunk
            GLOAD_LDS16(xb + (size_t)(m0 + idx * 16 + arow_l) * DI + k0 + asrc_l,
                        &As[idx * 512]);
        }
        {   // B transposed, vectorized: Bs[n][k] = w[k0+k][n0+n]
            const int kq = (tid >> 5) * 4;
            const int nq = (tid & 31) * 4;
            float va[4][4];
            #pragma unroll
            for (int d = 0; d < 4; ++d)
                *(float4*)va[d] = *(const float4*)(w + (size_t)(k0 + kq + d) * DI + n0 + nq);
            #pragma unroll
            for (int i2 = 0; i2 < 4; ++i2) {
                ushort4 u;
                u.x = f2bf(va[0][i2]); u.y = f2bf(va[1][i2]);
                u.z = f2bf(va[2][i2]); u.w = f2bf(va[3][i2]);
                *(ushort4*)&Bs[(nq + i2) * LDT + kq] = u;
            }
        }
        __syncthreads();
        s16x8 af[4], bfr[4];
        #pragma unroll
        for (int fr = 0; fr < 4; ++fr) {
            const int arow = wr * 64 + fr * 16 + r;
            af[fr] = *(const s16x8*)((const char*)As + arow * 64 + ((g * 16) ^ ((arow & 1) << 5)));
        }
        #pragma unroll
        for (int cf = 0; cf < 4; ++cf)
            bfr[cf] = *(const s16x8*)&Bs[(wc * 64 + cf * 16 + r) * LDT + g * 8];
        #pragma unroll
        for (int fr = 0; fr < 4; ++fr)
            #pragma unroll
            for (int cf = 0; cf < 4; ++cf)
                acc[fr][cf] = __builtin_amdgcn_mfma_f32_16x16x32_bf16(af[fr], bfr[cf], acc[fr][cf], 0, 0, 0);
        __syncthreads();
    }

    const float scale = (which == 0) ? 0.03608439182435161f : 1.0f;
    if (which < 2) {
        unsigned short* O = ws + (size_t)which * QK_ELEMS;
        #pragma unroll
        for (int fr = 0; fr < 4; ++fr)
            #pragma unroll
            for (int cf = 0; cf < 4; ++cf) {
                int row = m0 + wr * 64 + fr * 16 + g * 4;
                int col = n0 + wc * 64 + cf * 16 + r;
                #pragma unroll
                for (int jj = 0; jj < 4; ++jj) {
                    int rr = row + jj;
                    int cc = col ^ ((rr & 7) << 3);           // Q and K pre-swizzle
                    O[(size_t)rr * DI + cc] = f2bf(acc[fr][cf][jj] * scale);
                }
            }
    } else {
        unsigned short* O = ws + 2 * QK_ELEMS; // Vf fragment-packed
        #pragma unroll
        for (int fr = 0; fr < 4; ++fr)
            #pragma unroll
            for (int cf = 0; cf < 4; ++cf) {
                int row = m0 + wr * 64 + fr * 16 + g * 4;   // = b*2048 + s
                int bb = row >> 11;
                int st = (row & 2047) >> 4;
                int et = ((n0 + wc * 64) >> 4) + cf;
                ushort4 pk;
                pk.x = f2bf(acc[fr][cf][0]); pk.y = f2bf(acc[fr][cf][1]);
                pk.z = f2bf(acc[fr][cf][2]); pk.w = f2bf(acc[fr][cf][3]);
                *(ushort4*)&O[(((size_t)bb * 128 + st) * 48 + et) * 256 + lane * 4] = pk;
            }
    }
}

// ---------------- fused causal attention -------------------------------------
// 512 threads = 8 waves; block owns q-pair (jbase, jbase+1); passes (2a,2a+1)
// then (126-2a,127-2a). K (96KB) AND Q (48KB, per pass) staged via
// global_load_lds, swizzled. V prefetched to REGISTERS at tile start (issued
// BEFORE the next-tile stage, so PV consumes at vmcnt(12), stage stays in
// flight). Barriers B and C are lgkm-only; only barrier A drains vmcnt.
__global__ __launch_bounds__(512, 1) void attn_kernel(
    const unsigned short* __restrict__ ws, float* __restrict__ out)
{
    __shared__ unsigned short Ks[64 * 768];     // 96 KB
    __shared__ unsigned short Qs[32 * 768];     // 48 KB (q-pair, swizzled)
    __shared__ unsigned short P_lds[2048];      // [qsel][slice][16q][16k]
    __shared__ float redm[128];                 // [qsel][slice][16q]

    const int id = blockIdx.x;
    const int b = id & 7;                  // one batch per XCD
    const int a = id >> 3;                 // 0..31
    const int tid = threadIdx.x;
    const int wid = tid >> 6, lane = tid & 63;
    const int qsel = wid >> 2;             // q-tile of the pair
    const int wv = wid & 3;                // k-slice & e-quarter owner
    const int r = lane & 15, g = lane >> 4;
    const int e0 = wv * 192;
    const int rw = wv * 16 + r;
    const int swz = (r & 7) << 4;

    const unsigned short* Qb = ws + (size_t)b * SS * DI;                // swizzled
    const unsigned short* Kb = ws + QK_ELEMS + (size_t)b * SS * DI;     // swizzled
    const unsigned short* Vf = ws + 2 * QK_ELEMS + (size_t)b * 128 * 48 * 256;
    float* Ob = out + (size_t)b * SS * DI;
    const char* KsB = (const char*)Ks;
    const char* QsB = (const char*)Qs;

#define STAGEK(KT) do { \
        const size_t sbase_ = (size_t)(KT) * 64 * DI; \
        _Pragma("unroll") \
        for (int i_ = 0; i_ < 12; ++i_) { \
            const int idx_ = wid * 12 + i_; \
            GLOAD_LDS16(Kb + sbase_ + idx_ * 512 + lane * 8, &Ks[idx_ * 512]); \
        } \
    } while (0)

#define RAWBAR() do { \
        asm volatile("s_waitcnt lgkmcnt(0)" ::: "memory"); \
        __builtin_amdgcn_sched_barrier(0); \
        __builtin_amdgcn_s_barrier(); \
        __builtin_amdgcn_sched_barrier(0); \
    } while (0)

    for (int pp = 0; pp < 2; ++pp) {
        const int jbase = pp ? (126 - 2 * a) : (2 * a);
        const int j = jbase + qsel;
        const int q0 = j * 16;
        const int nt_own = (q0 + 79) >> 6;
        const int ntmax = (16 * (jbase + 1) + 79) >> 6;

        // stage Q pair (flat 48KB copy; rows contiguous) + first K tile
        {
            const size_t qsb = (size_t)jbase * 16 * DI;
            #pragma unroll
            for (int i_ = 0; i_ < 6; ++i_) {
                const int idx_ = wid * 6 + i_;
                GLOAD_LDS16(Qb + qsb + idx_ * 512 + lane * 8, &Qs[idx_ * 512]);
            }
        }
        STAGEK(0);

        f32x4 acc[12];
        #pragma unroll
        for (int cf = 0; cf < 12; ++cf) acc[cf] = (f32x4){0.f, 0.f, 0.f, 0.f};
        float m = -1e30f, lp = 0.f;

        for (int kt = 0; kt < ntmax; ++kt) {
            const int k0 = kt * 64;
            const bool act = kt < nt_own;
            __syncthreads();                        // A: K(kt)+Q staged (vmcnt drain)

            f32x4 s = {0.f, 0.f, 0.f, 0.f};
            s16x4 va[4][12];
            if (act) {
                // V prefetch FIRST (before any later stage in issue order)
                const size_t vbase = ((size_t)(k0 >> 4) * 48 + (e0 >> 4)) * 256 + lane * 4;
                #pragma unroll
                for (int ks = 0; ks < 4; ++ks)
                    #pragma unroll
                    for (int cf = 0; cf < 12; ++cf)
                        va[ks][cf] = *(const s16x4*)(Vf + vbase + (size_t)ks * 48 * 256 + cf * 256);

                f32x4 sa = {0,0,0,0}, sb = {0,0,0,0};
                #pragma unroll
                for (int t = 0; t < 24; t += 2) {
                    const int c0 = (t * 64 + g * 16) ^ swz;
                    const int c1 = (t * 64 + 64 + g * 16) ^ swz;
                    s16x8 qa = *(const s16x8*)(QsB + qsel * 24576 + r * 1536 + c0);
                    s16x8 qb2 = *(const s16x8*)(QsB + qsel * 24576 + r * 1536 + c1);
                    s16x8 ka = *(const s16x8*)(KsB + rw * 1536 + c0);
                    s16x8 kb2 = *(const s16x8*)(KsB + rw * 1536 + c1);
                    sa = __builtin_amdgcn_mfma_f32_16x16x32_bf16(ka, qa, sa, 0, 0, 0);
                    sb = __builtin_amdgcn_mfma_f32_16x16x32_bf16(kb2, qb2, sb, 0, 0, 0);
                }
                #pragma unroll
                for (int jj = 0; jj < 4; ++jj) s[jj] = sa[jj] + sb[jj];
                if (k0 + 64 > q0) {                 // boundary: causal mask
                    #pragma unroll
                    for (int jj = 0; jj < 4; ++jj)
                        if (k0 + 16 * wv + 4 * g + jj > q0 + r) s[jj] = -1e30f;
                }
                float v = fmaxf(fmaxf(s[0], s[1]), fmaxf(s[2], s[3]));
                v = fmaxf(v, __shfl_xor(v, 16));
                v = fmaxf(v, __shfl_xor(v, 32));
                if (lane < 16) redm[qsel * 64 + wv * 16 + lane] = v;
            }
            RAWBAR();                               // B: maxes visible, K consumed

            if (kt + 1 < ntmax) STAGEK(kt + 1);     // flies until next barrier A

            if (act) {
                const float* rq = &redm[qsel * 64];
                float vmax = fmaxf(fmaxf(rq[r], rq[16 + r]), fmaxf(rq[32 + r], rq[48 + r]));
                if (__any(vmax > m + 8.0f)) {       // deferred rescale (THR=8)
                    const float mn = fmaxf(m, vmax);
                    const float alpha = __expf(m - mn);
                    m = mn;
                    lp *= alpha;
                    float al[4];
                    #pragma unroll
                    for (int jj = 0; jj < 4; ++jj) al[jj] = __shfl(alpha, 4 * g + jj);
                    #pragma unroll
                    for (int cf = 0; cf < 12; ++cf)
                        #pragma unroll
                        for (int jj = 0; jj < 4; ++jj) acc[cf][jj] *= al[jj];
                }
                s16x4 pw;
                #pragma unroll
                for (int jj = 0; jj < 4; ++jj) {
                    float p = __expf(s[jj] - m);
                    lp += p;
                    pw[jj] = (short)f2bf(p);
                }
                *(s16x4*)&P_lds[qsel * 1024 + wv * 256 + r * 16 + g * 4] = pw;
            }
            RAWBAR();                               // C: P ready (stage in flight)

            if (act) {
                s16x4 pa[4];
                #pragma unroll
                for (int ks = 0; ks < 4; ++ks)
                    pa[ks] = *(const s16x4*)&P_lds[qsel * 1024 + ks * 256 + r * 16 + g * 4];
                #pragma unroll
                for (int cf = 0; cf < 12; ++cf)
                    #pragma unroll
                    for (int ks = 0; ks < 4; ++ks)
                        acc[cf] = __builtin_amdgcn_mfma_f32_16x16x16bf16_1k(pa[ks], va[ks][cf], acc[cf], 0, 0, 0);
            }
        }
        // epilogue: combine per-slice lp, normalize, store
        lp += __shfl_xor(lp, 16);
        lp += __shfl_xor(lp, 32);
        if (lane < 16) redm[qsel * 64 + wv * 16 + lane] = lp;
        __syncthreads();
        const float* rq = &redm[qsel * 64];
        const float lt = rq[r] + rq[16 + r] + rq[32 + r] + rq[48 + r];
        const float linv = 1.0f / lt;
        float lv[4];
        #pragma unroll
        for (int jj = 0; jj < 4; ++jj) lv[jj] = __shfl(linv, 4 * g + jj);
        #pragma unroll
        for (int cf = 0; cf < 12; ++cf)
            #pragma unroll
            for (int jj = 0; jj < 4; ++jj)
                Ob[(size_t)(q0 + 4 * g + jj) * DI + e0 + cf * 16 + r] = acc[cf][jj] * lv[jj];
        __syncthreads();                            // Qs/P_lds safe to overwrite
    }
#undef STAGEK
#undef RAWBAR
}

extern "C" void kernel_launch(void* const* d_in, const int* in_sizes, int n_in,
                              void* d_out, int out_size, void* d_ws, size_t ws_size,
                              hipStream_t stream) {
    const float* x  = (const float*)d_in[0];
    const float* wq = (const float*)d_in[1];
    const float* wk = (const float*)d_in[2];
    const float* wv = (const float*)d_in[3];
    unsigned short* ws = (unsigned short*)d_ws;
    float* out = (float*)d_out;
    // stash bf16(x) in d_out (25 MB of its 50 MB); attn fully overwrites later
    unsigned short* xb = (unsigned short*)d_out;

    conv_kernel<<<(int)(QK_ELEMS / (256 * 8)), 256, 0, stream>>>(x, xb);
    proj_kernel<<<dim3(6, 128, 3), 256, 0, stream>>>(xb, wq, wk, wv, ws);
    attn_kernel<<<256, 512, 0, stream>>>(ws, out);
}